// Round 3
// baseline (137.503 us; speedup 1.0000x reference)
//
#include <hip/hip_runtime.h>
#include <hip/hip_bf16.h>

// 2-layer dense GAT, B=32, N=1024. ALL tensors fp32 (inputs per reference file;
// output fp32 confirmed by threshold arithmetic: no bf16 eps-floor applied).
// Layer1: H=3, F=4, O=2 -> fp32 ws. Layer2: H=1, F=6, O=4 -> fp32 d_out.
//
// Per (b,h,row-chunk) block: stage Wh (N x O) and s_dst (N) in LDS. Leaky-ReLU is
// monotone increasing, so the per-row softmax max is exactly LR(s_n + max_m d_m):
// one block-wide max replaces the per-row max pass (one-pass exact softmax).
// Inner m-loop is lane-uniform -> LDS broadcast reads, zero bank conflicts.

#define GAT_ALPHA 0.2f

template <int F, int O, int H>
__global__ __launch_bounds__(256) void gat_layer_kernel(
    const float* __restrict__ x,            // (B, N, F)
    const float* __restrict__ Wt,           // (H, F, O)
    const float* __restrict__ at,           // (H, 2*O)
    float* __restrict__ out)                // (B, N, H*O)
{
    constexpr int N = 1024;
    constexpr int ROWS = 256;              // rows per block == blockDim.x
    constexpr int CHUNKS = N / ROWS;       // 4

    const int bid   = blockIdx.x;
    const int chunk = bid % CHUNKS;
    const int h     = (bid / CHUNKS) % H;
    const int b     = bid / (CHUNKS * H);
    const int tid   = threadIdx.x;

    // Per-head weights -> registers (tiny, L2-resident)
    float Wl[F][O];
#pragma unroll
    for (int f = 0; f < F; ++f)
#pragma unroll
        for (int o = 0; o < O; ++o)
            Wl[f][o] = Wt[(h * F + f) * O + o];

    float asrc[O], adst[O];
#pragma unroll
    for (int o = 0; o < O; ++o) {
        asrc[o] = at[h * 2 * O + o];
        adst[o] = at[h * 2 * O + O + o];
    }

    __shared__ float sWh[N * O];   // Wh[m][o]
    __shared__ float sd[N];        // s_dst[m]
    __shared__ float sred[4];      // per-wave max scratch

    // Stage Wh and s_dst for the whole (b,h) into LDS; track local max of d.
    const float* xb = x + (size_t)b * N * F;
    float dmax = -3.0e38f;
    for (int m = tid; m < N; m += 256) {
        float xv[F];
#pragma unroll
        for (int f = 0; f < F; ++f) xv[f] = xb[m * F + f];
        float d = 0.0f;
#pragma unroll
        for (int o = 0; o < O; ++o) {
            float wh = 0.0f;
#pragma unroll
            for (int f = 0; f < F; ++f) wh += xv[f] * Wl[f][o];
            sWh[m * O + o] = wh;
            d += wh * adst[o];
        }
        sd[m] = d;
        dmax = fmaxf(dmax, d);
    }

    // Block-wide max of s_dst (wave butterfly + 4-slot LDS combine)
#pragma unroll
    for (int off = 32; off > 0; off >>= 1)
        dmax = fmaxf(dmax, __shfl_xor(dmax, off, 64));
    if ((tid & 63) == 0) sred[tid >> 6] = dmax;
    __syncthreads();
    const float D = fmaxf(fmaxf(sred[0], sred[1]), fmaxf(sred[2], sred[3]));

    // One thread per output row n.
    const int n = chunk * ROWS + tid;
    float sn = 0.0f;
#pragma unroll
    for (int o = 0; o < O; ++o) sn += sWh[n * O + o] * asrc[o];

    // exact row max of LR(sn + d_m), by monotonicity of leaky-relu
    const float eMraw = sn + D;
    const float eM = fmaxf(eMraw, GAT_ALPHA * eMraw);

    float den = 0.0f;
    float num[O];
#pragma unroll
    for (int o = 0; o < O; ++o) num[o] = 0.0f;

#pragma unroll 4
    for (int m = 0; m < N; ++m) {            // lane-uniform m -> LDS broadcasts
        const float e0 = sn + sd[m];
        const float e  = fmaxf(e0, GAT_ALPHA * e0);   // leaky-relu
        const float w  = __expf(e - eM);              // <= 1, exact-stable
        den += w;
#pragma unroll
        for (int o = 0; o < O; ++o) num[o] += w * sWh[m * O + o];
    }

    const float inv = 1.0f / den;            // den >= 1 (max term contributes 1)
    const size_t base = ((size_t)b * N + n) * (H * O) + (size_t)h * O;
#pragma unroll
    for (int o = 0; o < O; ++o) {
        float v = num[o] * inv;
        v = (v > 0.0f) ? v : (__expf(v) - 1.0f);   // ELU(alpha=1)
        out[base + o] = v;
    }
}

extern "C" void kernel_launch(void* const* d_in, const int* in_sizes, int n_in,
                              void* d_out, int out_size, void* d_ws, size_t ws_size,
                              hipStream_t stream) {
    const float* x  = (const float*)d_in[0];  // (32,1024,4)
    const float* W1 = (const float*)d_in[1];  // (3,4,2)
    const float* a1 = (const float*)d_in[2];  // (3,4,1)
    const float* W2 = (const float*)d_in[3];  // (1,6,4)
    const float* a2 = (const float*)d_in[4];  // (1,8,1)

    float* h1 = (float*)d_ws;     // (32,1024,6) fp32 = 768 KiB scratch
    float* y  = (float*)d_out;    // (32,1024,4) fp32

    constexpr int B = 32;
    // Layer 1: H=3, F=4, O=2; grid = B*H*chunks
    gat_layer_kernel<4, 2, 3><<<B * 3 * 4, 256, 0, stream>>>(x, W1, a1, h1);
    // Layer 2: H=1, F=6, O=4
    gat_layer_kernel<6, 4, 1><<<B * 1 * 4, 256, 0, stream>>>(h1, W2, a2, y);
}

// Round 4
// 97.766 us; speedup vs baseline: 1.4064x; 1.4064x over previous
//
#include <hip/hip_runtime.h>
#include <type_traits>

// 2-layer dense GAT, B=32, N=1024, all fp32. L1: H=3,F=4,O=2 -> ws. L2: H=1,F=6,O=4 -> out.
//
// Round-4 structure: per (b,h,64-row-chunk) block of 256 threads laid out as
// 16 rows x 16 m-slices. Each thread accumulates R=4 rows over its 64-element
// m-slice (m = mi*16 + s, interleaved -> conflict-free broadcast LDS reads),
// amortizing each staged (d, Wh) read over 4 rows and giving 4 independent
// accumulation chains. Cross-slice reduction via LDS at the end.
// Softmax max is exact & one-pass: leaky-relu monotone => row max = LR(sn + max_m d_m).
// LDS stages pre-scaled dA = d*log2e, dB = 0.2*d*log2e so the inner loop is
// add,add,max,exp2 + (1+O) FMAs per row.

#define GAT_ALPHA 0.2f
#define LOG2E 1.44269504088896f

template <int F, int O, int H>
__global__ __launch_bounds__(256) void gat_layer_kernel(
    const float* __restrict__ x,            // (B, N, F)
    const float* __restrict__ Wt,           // (H, F, O)
    const float* __restrict__ at,           // (H, 2*O)
    float* __restrict__ out)                // (B, N, H*O)
{
    constexpr int N = 1024;
    constexpr int NT = 256;          // threads per block
    constexpr int RPB = 64;          // rows per block
    constexpr int S = 16;            // m-slices per block
    constexpr int R = 4;             // rows per thread
    constexpr int Q = O + 1;         // den + num[O]
    constexpr int CHUNKS = N / RPB;  // 16

    const int bid   = blockIdx.x;
    const int chunk = bid & (CHUNKS - 1);
    const int h     = (bid >> 4) % H;
    const int b     = bid / (CHUNKS * H);
    const int tid   = threadIdx.x;
    const int r     = tid & 15;      // row group
    const int s     = tid >> 4;      // m-slice

    // Per-head weights -> registers (uniform per block -> scalar loads)
    float Wl[F][O];
#pragma unroll
    for (int f = 0; f < F; ++f)
#pragma unroll
        for (int o = 0; o < O; ++o)
            Wl[f][o] = Wt[(h * F + f) * O + o];

    float asrc[O], adst[O];
#pragma unroll
    for (int o = 0; o < O; ++o) {
        asrc[o] = at[h * 2 * O + o];
        adst[o] = at[h * 2 * O + O + o];
    }

    __shared__ float2 sdAB[N];            // (d*log2e, 0.2*d*log2e)
    __shared__ float  sWh[N * O];         // Wh[m][o]
    __shared__ float  sred[4];            // wave-max scratch
    __shared__ float  sredu[RPB * S * Q]; // [s][r][j][q]
    __shared__ float  ssum[RPB * Q];      // reduced per-row sums

    // ---- Stage Wh, dA/dB for the whole (b,h); track max d ----
    const float* xb = x + (size_t)b * N * F;
    float dmax = -3.0e38f;
    for (int m = tid; m < N; m += NT) {
        float xv[F];
#pragma unroll
        for (int f = 0; f < F; ++f) xv[f] = xb[(size_t)m * F + f];
        float d = 0.0f;
#pragma unroll
        for (int o = 0; o < O; ++o) {
            float wh = 0.0f;
#pragma unroll
            for (int f = 0; f < F; ++f) wh += xv[f] * Wl[f][o];
            sWh[m * O + o] = wh;
            d += wh * adst[o];
        }
        sdAB[m] = make_float2(d * LOG2E, d * (GAT_ALPHA * LOG2E));
        dmax = fmaxf(dmax, d);
    }
#pragma unroll
    for (int off = 32; off > 0; off >>= 1)
        dmax = fmaxf(dmax, __shfl_xor(dmax, off, 64));
    if ((tid & 63) == 0) sred[tid >> 6] = dmax;
    __syncthreads();
    const float D = fmaxf(fmaxf(sred[0], sred[1]), fmaxf(sred[2], sred[3]));

    // ---- Per-row constants: t1 = (sn-eM)*log2e, t2 = (0.2sn-eM)*log2e ----
    float t1[R], t2[R];
#pragma unroll
    for (int j = 0; j < R; ++j) {
        const int row = chunk * RPB + r + 16 * j;
        float sn = 0.0f;
#pragma unroll
        for (int o = 0; o < O; ++o) sn += sWh[row * O + o] * asrc[o];
        const float e0m = sn + D;                         // row max pre-LR
        const float eM  = fmaxf(e0m, GAT_ALPHA * e0m);    // exact row max of LR
        t1[j] = (sn - eM) * LOG2E;
        t2[j] = (GAT_ALPHA * sn - eM) * LOG2E;
    }

    // ---- Inner loop: this thread's m-slice (stride-16 interleave), 4 rows ----
    float den[R];
    float num[R][O];
#pragma unroll
    for (int j = 0; j < R; ++j) {
        den[j] = 0.0f;
#pragma unroll
        for (int o = 0; o < O; ++o) num[j][o] = 0.0f;
    }

    using WVec = typename std::conditional<O == 2, float2, float4>::type;
    const WVec* sWhV = (const WVec*)sWh;

#pragma unroll 4
    for (int mi = 0; mi < N / S; ++mi) {
        const int m = mi * S + s;            // wave lanes: 4 consecutive m -> no conflicts
        const float2 ab = sdAB[m];
        const WVec  wv = sWhV[m];
        const float* wp = (const float*)&wv;
#pragma unroll
        for (int j = 0; j < R; ++j) {
            const float arg = fmaxf(ab.x + t1[j], ab.y + t2[j]); // (LR(e0)-eM)*log2e <= 0
            const float w   = __builtin_amdgcn_exp2f(arg);
            den[j] += w;
#pragma unroll
            for (int o = 0; o < O; ++o) num[j][o] += w * wp[o];
        }
    }

    // ---- Cross-slice reduction ----
#pragma unroll
    for (int j = 0; j < R; ++j) {
        float* p = &sredu[(((s * 16) + r) * R + j) * Q];
        p[0] = den[j];
#pragma unroll
        for (int o = 0; o < O; ++o) p[1 + o] = num[j][o];
    }
    __syncthreads();

    for (int idx = tid; idx < RPB * Q; idx += NT) {
        const int rowl = idx / Q, q = idx % Q;
        const int rr = rowl & 15, jj = rowl >> 4;
        float acc = 0.0f;
#pragma unroll
        for (int ss = 0; ss < S; ++ss)
            acc += sredu[(((ss * 16) + rr) * R + jj) * Q + q];
        ssum[rowl * Q + q] = acc;
    }
    __syncthreads();

    // ---- Finalize: softmax divide + ELU + store ----
    for (int idx = tid; idx < RPB * O; idx += NT) {
        const int rowl = idx / O, o = idx % O;
        const float inv = 1.0f / ssum[rowl * Q];           // den >= 1
        float v = ssum[rowl * Q + 1 + o] * inv;
        v = (v > 0.0f) ? v : (__expf(v) - 1.0f);           // ELU(alpha=1)
        const int row = chunk * RPB + rowl;
        out[((size_t)b * N + row) * (H * O) + h * O + o] = v;
    }
}

extern "C" void kernel_launch(void* const* d_in, const int* in_sizes, int n_in,
                              void* d_out, int out_size, void* d_ws, size_t ws_size,
                              hipStream_t stream) {
    const float* x  = (const float*)d_in[0];  // (32,1024,4)
    const float* W1 = (const float*)d_in[1];  // (3,4,2)
    const float* a1 = (const float*)d_in[2];  // (3,4,1)
    const float* W2 = (const float*)d_in[3];  // (1,6,4)
    const float* a2 = (const float*)d_in[4];  // (1,8,1)

    float* h1 = (float*)d_ws;     // (32,1024,6) fp32 = 768 KiB scratch
    float* y  = (float*)d_out;    // (32,1024,4) fp32

    constexpr int B = 32;
    // Layer 1: H=3, F=4, O=2; grid = B*H*16 = 1536 blocks
    gat_layer_kernel<4, 2, 3><<<B * 3 * 16, 256, 0, stream>>>(x, W1, a1, h1);
    // Layer 2: H=1, F=6, O=4; grid = B*16 = 512 blocks
    gat_layer_kernel<6, 4, 1><<<B * 1 * 16, 256, 0, stream>>>(h1, W2, a2, y);
}

// Round 5
// 93.139 us; speedup vs baseline: 1.4763x; 1.0497x over previous
//
#include <hip/hip_runtime.h>

// 2-layer dense GAT, B=32, N=1024, all fp32. L1: H=3,F=4,O=2 -> ws. L2: H=1,F=6,O=4 -> out.
//
// Round-5: exp hoisted OUT of the N^2 loop. Leaky-relu has one kink, so
//   w = exp(LR(sn+dm)-eM) = (sn+dm>=0) ? c1[row]*E1[m] : c2[row]*E2[m]
// with E1[m]=e^{dm-D}, E2[m]=e^{0.2(dm-D)} staged once per (b,h) in LDS and
// c1,c2 one exp per row. All factors <= 1 (eM exact via LR monotonicity,
// D = max_m dm), so no overflow and den >= 1. Inner body is pure full-rate
// VALU: cmp + 2 mul + cndmask + (1+O) fma per (row,m).
// Block = 256 threads as 16 row-groups x 16 m-slices, R=8 rows/thread
// (128 rows/block): each staged (dm,E,Wh) LDS broadcast read is amortized
// over 8 rows; 8 independent accumulation chains for ILP.

#define GAT_ALPHA 0.2f
#define LOG2E 1.44269504088896f

template <int F, int O, int H>
__global__ __launch_bounds__(256) void gat_layer_kernel(
    const float* __restrict__ x,            // (B, N, F)
    const float* __restrict__ Wt,           // (H, F, O)
    const float* __restrict__ at,           // (H, 2*O)
    float* __restrict__ out)                // (B, N, H*O)
{
    constexpr int N = 1024, NT = 256, RPB = 128, S = 16, R = 8;
    constexpr int CHUNKS = N / RPB;      // 8
    constexpr int Q = O + 1;             // den + num[O]

    const int bid   = blockIdx.x;
    const int chunk = bid % CHUNKS;
    const int h     = (bid / CHUNKS) % H;
    const int b     = bid / (CHUNKS * H);
    const int tid   = threadIdx.x;
    const int r     = tid & 15;          // row group (16)
    const int s     = tid >> 4;          // m-slice (16)

    // Per-head weights (block-uniform -> scalar loads)
    float Wl[F][O];
#pragma unroll
    for (int f = 0; f < F; ++f)
#pragma unroll
        for (int o = 0; o < O; ++o)
            Wl[f][o] = Wt[(h * F + f) * O + o];

    float asrc[O], adst[O];
#pragma unroll
    for (int o = 0; o < O; ++o) {
        asrc[o] = at[h * 2 * O + o];
        adst[o] = at[h * 2 * O + O + o];
    }

    __shared__ __align__(16) float sWh[N * O];  // Wh[m][o]
    __shared__ float2 sE[N];                    // (E1, E2)
    __shared__ float  sdp[N];                   // raw d_m (for kink compare)
    __shared__ float  sred[4];
    __shared__ float  sredu[RPB * Q * S];       // [rowl][q][s]
    __shared__ float  ssum[RPB * Q];

    // ---- Phase A: stage Wh + d for whole (b,h); block max D ----
    const float* xb = x + (size_t)b * N * F;
    float dmax = -3.0e38f;
    for (int m = tid; m < N; m += NT) {
        float xv[F];
        if constexpr (F == 4) {
            const float4 v = ((const float4*)xb)[m];
            xv[0] = v.x; xv[1] = v.y; xv[2] = v.z; xv[3] = v.w;
        } else {
#pragma unroll
            for (int k = 0; k < F / 2; ++k) {
                const float2 v = ((const float2*)xb)[m * (F / 2) + k];
                xv[2 * k] = v.x; xv[2 * k + 1] = v.y;
            }
        }
        float d = 0.0f;
#pragma unroll
        for (int o = 0; o < O; ++o) {
            float wh = 0.0f;
#pragma unroll
            for (int f = 0; f < F; ++f) wh += xv[f] * Wl[f][o];
            sWh[m * O + o] = wh;
            d += wh * adst[o];
        }
        sdp[m] = d;
        dmax = fmaxf(dmax, d);
    }
#pragma unroll
    for (int off = 32; off > 0; off >>= 1)
        dmax = fmaxf(dmax, __shfl_xor(dmax, off, 64));
    if ((tid & 63) == 0) sred[tid >> 6] = dmax;
    __syncthreads();
    const float D = fmaxf(fmaxf(sred[0], sred[1]), fmaxf(sred[2], sred[3]));

    // ---- Phase B: per-m exp factors (N exps instead of N^2) ----
    for (int m = tid; m < N; m += NT) {          // same m's this thread wrote
        const float t = (sdp[m] - D) * LOG2E;
        sE[m] = make_float2(__builtin_amdgcn_exp2f(t),
                            __builtin_amdgcn_exp2f(GAT_ALPHA * t));
    }

    // ---- Per-row constants: thr, c1, c2 (one exp per row) ----
    float thr[R], c1[R], c2[R];
#pragma unroll
    for (int j = 0; j < R; ++j) {
        const int row = chunk * RPB + r + 16 * j;
        float sn = 0.0f;
#pragma unroll
        for (int o = 0; o < O; ++o) sn += sWh[row * O + o] * asrc[o];
        const float z = sn + D;                  // row max pre-LR
        const float e = __builtin_amdgcn_exp2f(-0.8f * LOG2E * fabsf(z));
        c1[j] = (z >= 0.0f) ? 1.0f : e;          // e^{sn+D-eM}
        c2[j] = (z >= 0.0f) ? e : 1.0f;          // e^{0.2(sn+D)-eM}
        thr[j] = -sn;                            // dm >= -sn <=> branch 1
    }
    __syncthreads();                             // sE visible to all

    // ---- Inner N^2/P loop: pure full-rate VALU ----
    float den[R], num[R][O];
#pragma unroll
    for (int j = 0; j < R; ++j) {
        den[j] = 0.0f;
#pragma unroll
        for (int o = 0; o < O; ++o) num[j][o] = 0.0f;
    }

#pragma unroll 4
    for (int mi = 0; mi < N / S; ++mi) {
        const int m = mi * S + s;                // 4 distinct m per wave -> broadcast, no conflicts
        const float  dm = sdp[m];
        const float2 E  = sE[m];
        float wp[O];
        if constexpr (O == 2) {
            const float2 wv = ((const float2*)sWh)[m];
            wp[0] = wv.x; wp[1] = wv.y;
        } else {
            const float4 wv = ((const float4*)sWh)[m];
            wp[0] = wv.x; wp[1] = wv.y; wp[2] = wv.z; wp[3] = wv.w;
        }
#pragma unroll
        for (int j = 0; j < R; ++j) {
            const float w = (dm >= thr[j]) ? (c1[j] * E.x) : (c2[j] * E.y);
            den[j] += w;
#pragma unroll
            for (int o = 0; o < O; ++o) num[j][o] += w * wp[o];
        }
    }

    // ---- Cross-slice reduction: sredu[(rowl*Q+q)*S + s] ----
#pragma unroll
    for (int j = 0; j < R; ++j) {
        const int rowl = r + 16 * j;
        sredu[(rowl * Q + 0) * S + s] = den[j];
#pragma unroll
        for (int o = 0; o < O; ++o)
            sredu[(rowl * Q + 1 + o) * S + s] = num[j][o];
    }
    __syncthreads();

    for (int idx = tid; idx < RPB * Q; idx += NT) {
        float acc = 0.0f;
#pragma unroll
        for (int ss = 0; ss < S; ++ss) acc += sredu[idx * S + ss];
        ssum[idx] = acc;
    }
    __syncthreads();

    // ---- Finalize: divide + ELU + store ----
    for (int idx = tid; idx < RPB * O; idx += NT) {
        const int rowl = idx / O, o = idx % O;
        const float inv = 1.0f / ssum[rowl * Q];           // den >= 1
        float v = ssum[rowl * Q + 1 + o] * inv;
        v = (v > 0.0f) ? v : (__expf(v) - 1.0f);           // ELU(alpha=1)
        const int row = chunk * RPB + rowl;
        out[((size_t)b * N + row) * (H * O) + h * O + o] = v;
    }
}

extern "C" void kernel_launch(void* const* d_in, const int* in_sizes, int n_in,
                              void* d_out, int out_size, void* d_ws, size_t ws_size,
                              hipStream_t stream) {
    const float* x  = (const float*)d_in[0];  // (32,1024,4)
    const float* W1 = (const float*)d_in[1];  // (3,4,2)
    const float* a1 = (const float*)d_in[2];  // (3,4,1)
    const float* W2 = (const float*)d_in[3];  // (1,6,4)
    const float* a2 = (const float*)d_in[4];  // (1,8,1)

    float* h1 = (float*)d_ws;     // (32,1024,6) fp32 = 768 KiB scratch
    float* y  = (float*)d_out;    // (32,1024,4) fp32

    constexpr int B = 32;
    // Layer 1: H=3, F=4, O=2; grid = B*H*8 = 768 blocks (3/CU)
    gat_layer_kernel<4, 2, 3><<<B * 3 * 8, 256, 0, stream>>>(x, W1, a1, h1);
    // Layer 2: H=1, F=6, O=4; grid = B*8 = 256 blocks
    gat_layer_kernel<6, 4, 1><<<B * 1 * 8, 256, 0, stream>>>(h1, W2, a2, y);
}